// Round 1
// baseline (4167.620 us; speedup 1.0000x reference)
//
#include <hip/hip_runtime.h>

#define NHW 9216      // 96*96
#define NCH 256       // channels
#define SCALE 0.0625f // 1/sqrt(256)

// ---------------------------------------------------------------------------
// Kernel 1: Zpart[split][n] = sum over this split's m of exp(S[n,m])
// S[n,m] = SCALE * sum_c fm[c,n]*ft[c,m].  Grid (144 n-tiles, 4 m-splits).
// ---------------------------------------------------------------------------
__global__ __launch_bounds__(256) void k_stats(const float* __restrict__ fm,
                                               const float* __restrict__ ft,
                                               float* __restrict__ Zpart) {
    __shared__ float smA[16][64];
    __shared__ float smB[16][64];
    const int tid = threadIdx.x;
    const int ty = tid >> 4, tx = tid & 15;
    const int n0 = blockIdx.x * 64;
    const int mbase = blockIdx.y * 2304;
    const int lk = ty, lo = tx * 4;
    float zacc[4] = {0.f, 0.f, 0.f, 0.f};

    for (int mt = 0; mt < 36; ++mt) {
        const int m0 = mbase + mt * 64;
        float acc[4][4] = {};
        for (int cc = 0; cc < 16; ++cc) {
            __syncthreads();
            const int c = cc * 16 + lk;
            *(float4*)(&smA[lk][lo]) = *(const float4*)(fm + (size_t)c * NHW + n0 + lo);
            *(float4*)(&smB[lk][lo]) = *(const float4*)(ft + (size_t)c * NHW + m0 + lo);
            __syncthreads();
#pragma unroll
            for (int kc = 0; kc < 16; ++kc) {
                const float4 av = *(const float4*)(&smA[kc][ty * 4]);
                const float4 bv = *(const float4*)(&smB[kc][tx * 4]);
                const float a[4] = {av.x, av.y, av.z, av.w};
                const float b[4] = {bv.x, bv.y, bv.z, bv.w};
#pragma unroll
                for (int i = 0; i < 4; i++)
#pragma unroll
                    for (int j = 0; j < 4; j++) acc[i][j] += a[i] * b[j];
            }
        }
#pragma unroll
        for (int i = 0; i < 4; i++) {
            float s = 0.f;
#pragma unroll
            for (int j = 0; j < 4; j++) s += __expf(acc[i][j] * SCALE);
            zacc[i] += s;
        }
    }
    // reduce each row over the 16 tx lanes (contiguous lanes within a wave)
#pragma unroll
    for (int i = 0; i < 4; i++) {
        float v = zacc[i];
        v += __shfl_xor(v, 1, 64);
        v += __shfl_xor(v, 2, 64);
        v += __shfl_xor(v, 4, 64);
        v += __shfl_xor(v, 8, 64);
        if (tx == 0) Zpart[(size_t)blockIdx.y * NHW + n0 + ty * 4 + i] = v;
    }
}

// ---------------------------------------------------------------------------
// Kernel 2: Gt[n*256+o] = (sum_c W1[o,c]*fm[c,n]) / Z[n]
// W1[o,c] = tw[o*512+c].  Grid (144 n-tiles, 4 o-tiles).
// ---------------------------------------------------------------------------
__global__ __launch_bounds__(256) void k_g(const float* __restrict__ fm,
                                           const float* __restrict__ tw,
                                           const float* __restrict__ Zpart,
                                           float* __restrict__ Gt) {
    __shared__ float smN[16][64];
    __shared__ float smO[16][64];
    const int tid = threadIdx.x;
    const int ty = tid >> 4, tx = tid & 15;
    const int n0 = blockIdx.x * 64, o0 = blockIdx.y * 64;
    const int lk = ty, lo = tx * 4;
    const int woo = tid & 63, wkk = (tid >> 6) * 4;
    float acc[4][4] = {};

    for (int cc = 0; cc < 16; ++cc) {
        __syncthreads();
        *(float4*)(&smN[lk][lo]) = *(const float4*)(fm + (size_t)(cc * 16 + lk) * NHW + n0 + lo);
        const float4 wv = *(const float4*)(tw + (size_t)(o0 + woo) * 512 + cc * 16 + wkk);
        smO[wkk + 0][woo] = wv.x;
        smO[wkk + 1][woo] = wv.y;
        smO[wkk + 2][woo] = wv.z;
        smO[wkk + 3][woo] = wv.w;
        __syncthreads();
#pragma unroll
        for (int kc = 0; kc < 16; kc++) {
            const float4 av = *(const float4*)(&smN[kc][ty * 4]);  // n rows
            const float4 bv = *(const float4*)(&smO[kc][tx * 4]);  // o cols
            const float a[4] = {av.x, av.y, av.z, av.w};
            const float b[4] = {bv.x, bv.y, bv.z, bv.w};
#pragma unroll
            for (int i = 0; i < 4; i++)
#pragma unroll
                for (int j = 0; j < 4; j++) acc[i][j] += a[i] * b[j];
        }
    }
#pragma unroll
    for (int i = 0; i < 4; i++) {
        const int n = n0 + ty * 4 + i;
        const float z = Zpart[n] + Zpart[NHW + n] + Zpart[2 * NHW + n] + Zpart[3 * NHW + n];
        const float zi = 1.f / z;
        float4 v;
        v.x = acc[i][0] * zi; v.y = acc[i][1] * zi; v.z = acc[i][2] * zi; v.w = acc[i][3] * zi;
        *(float4*)(Gt + (size_t)n * NCH + o0 + tx * 4) = v;
    }
}

// ---------------------------------------------------------------------------
// Kernel 3: out[o*NHW+m] = sum_c W2[o,c]*ft[c,m] + b[o]
// W2[o,c] = tw[o*512+256+c].  Grid (144 m-tiles, 4 o-tiles).
// ---------------------------------------------------------------------------
__global__ __launch_bounds__(256) void k_base(const float* __restrict__ ft,
                                              const float* __restrict__ tw,
                                              const float* __restrict__ tb,
                                              float* __restrict__ out) {
    __shared__ float smM[16][64];
    __shared__ float smO[16][64];
    const int tid = threadIdx.x;
    const int ty = tid >> 4, tx = tid & 15;
    const int m0 = blockIdx.x * 64, o0 = blockIdx.y * 64;
    const int lk = ty, lo = tx * 4;
    const int woo = tid & 63, wkk = (tid >> 6) * 4;
    float acc[4][4] = {};

    for (int cc = 0; cc < 16; ++cc) {
        __syncthreads();
        *(float4*)(&smM[lk][lo]) = *(const float4*)(ft + (size_t)(cc * 16 + lk) * NHW + m0 + lo);
        const float4 wv = *(const float4*)(tw + (size_t)(o0 + woo) * 512 + 256 + cc * 16 + wkk);
        smO[wkk + 0][woo] = wv.x;
        smO[wkk + 1][woo] = wv.y;
        smO[wkk + 2][woo] = wv.z;
        smO[wkk + 3][woo] = wv.w;
        __syncthreads();
#pragma unroll
        for (int kc = 0; kc < 16; kc++) {
            const float4 av = *(const float4*)(&smO[kc][ty * 4]);  // o rows
            const float4 bv = *(const float4*)(&smM[kc][tx * 4]);  // m cols
            const float a[4] = {av.x, av.y, av.z, av.w};
            const float b[4] = {bv.x, bv.y, bv.z, bv.w};
#pragma unroll
            for (int i = 0; i < 4; i++)
#pragma unroll
                for (int j = 0; j < 4; j++) acc[i][j] += a[i] * b[j];
        }
    }
#pragma unroll
    for (int i = 0; i < 4; i++) {
        const int o = o0 + ty * 4 + i;
        const float bb = tb[o];
        float4 v;
        v.x = acc[i][0] + bb; v.y = acc[i][1] + bb; v.z = acc[i][2] + bb; v.w = acc[i][3] + bb;
        *(float4*)(out + (size_t)o * NHW + m0 + tx * 4) = v;
    }
}

// ---------------------------------------------------------------------------
// Kernel 4: out[o,m] += sum_n Gt[n,o] * exp(SCALE * sum_c fm[c,n]*ft[c,m])
// Grid (144 m-tiles, 2 o-halves of 128, 2 n-splits of 72 tiles). Each block:
// per 64-wide n-tile: phase1 compute S tile (64n x 64m) -> exp -> LDS;
// phase2 accumulate acc2[128o x 64m] += G-tile @ E-tile.
// ---------------------------------------------------------------------------
__global__ __launch_bounds__(256) void k_main(const float* __restrict__ fm,
                                              const float* __restrict__ ft,
                                              const float* __restrict__ Gt,
                                              float* __restrict__ out) {
    __shared__ float smA[16][64];
    __shared__ float smB[16][64];
    __shared__ float smG[16][128];
    __shared__ float smE[64][68];
    const int tid = threadIdx.x;
    const int ty = tid >> 4, tx = tid & 15;
    const int m0 = blockIdx.x * 64;
    const int o0 = blockIdx.y * 128;
    const int ntbase = blockIdx.z * 72;
    const int lk = ty, lo = tx * 4;
    float acc2[8][4] = {};

    for (int nt = ntbase; nt < ntbase + 72; ++nt) {
        const int n0 = nt * 64;
        // ---- phase 1: S tile ----
        float acc[4][4] = {};
        for (int cc = 0; cc < 16; ++cc) {
            __syncthreads();
            *(float4*)(&smA[lk][lo]) = *(const float4*)(fm + (size_t)(cc * 16 + lk) * NHW + n0 + lo);
            *(float4*)(&smB[lk][lo]) = *(const float4*)(ft + (size_t)(cc * 16 + lk) * NHW + m0 + lo);
            __syncthreads();
#pragma unroll
            for (int kc = 0; kc < 16; kc++) {
                const float4 av = *(const float4*)(&smA[kc][ty * 4]);  // n
                const float4 bv = *(const float4*)(&smB[kc][tx * 4]);  // m
                const float a[4] = {av.x, av.y, av.z, av.w};
                const float b[4] = {bv.x, bv.y, bv.z, bv.w};
#pragma unroll
                for (int i = 0; i < 4; i++)
#pragma unroll
                    for (int j = 0; j < 4; j++) acc[i][j] += a[i] * b[j];
            }
        }
        // write E = exp(S*SCALE) to LDS (prev phase2 finished at its last barrier)
#pragma unroll
        for (int i = 0; i < 4; i++) {
            float4 e;
            e.x = __expf(acc[i][0] * SCALE);
            e.y = __expf(acc[i][1] * SCALE);
            e.z = __expf(acc[i][2] * SCALE);
            e.w = __expf(acc[i][3] * SCALE);
            *(float4*)(&smE[ty * 4 + i][tx * 4]) = e;
        }
        // ---- phase 2: acc2 += G(128o x 64n) * E(64n x 64m) ----
#pragma unroll
        for (int nkc = 0; nkc < 4; nkc++) {
            __syncthreads();  // smE visible; prev smG chunk reads done
            const size_t grow = (size_t)(n0 + nkc * 16 + ty) * NCH + o0 + tx * 8;
            *(float4*)(&smG[ty][tx * 8]) = *(const float4*)(Gt + grow);
            *(float4*)(&smG[ty][tx * 8 + 4]) = *(const float4*)(Gt + grow + 4);
            __syncthreads();
#pragma unroll
            for (int kr = 0; kr < 16; kr++) {
                const float4 g0 = *(const float4*)(&smG[kr][ty * 8]);
                const float4 g1 = *(const float4*)(&smG[kr][ty * 8 + 4]);
                const float4 ev = *(const float4*)(&smE[nkc * 16 + kr][tx * 4]);
                const float g[8] = {g0.x, g0.y, g0.z, g0.w, g1.x, g1.y, g1.z, g1.w};
                const float e[4] = {ev.x, ev.y, ev.z, ev.w};
#pragma unroll
                for (int i = 0; i < 8; i++)
#pragma unroll
                    for (int j = 0; j < 4; j++) acc2[i][j] += g[i] * e[j];
            }
        }
    }
    // accumulate into out (k_base wrote the base term); two n-split blocks add
#pragma unroll
    for (int i = 0; i < 8; i++) {
        float* p = out + (size_t)(o0 + ty * 8 + i) * NHW + m0 + tx * 4;
        atomicAdd(p + 0, acc2[i][0]);
        atomicAdd(p + 1, acc2[i][1]);
        atomicAdd(p + 2, acc2[i][2]);
        atomicAdd(p + 3, acc2[i][3]);
    }
}

extern "C" void kernel_launch(void* const* d_in, const int* in_sizes, int n_in,
                              void* d_out, int out_size, void* d_ws, size_t ws_size,
                              hipStream_t stream) {
    const float* fm = (const float*)d_in[0];
    const float* ft = (const float*)d_in[1];
    const float* tw = (const float*)d_in[2];
    const float* tb = (const float*)d_in[3];
    float* out = (float*)d_out;
    // workspace layout: Zpart [4][9216] f32, then Gt [9216][256] f32 (~9.6 MB)
    float* Zpart = (float*)d_ws;
    float* Gt = (float*)((char*)d_ws + (size_t)4 * NHW * sizeof(float));

    k_stats<<<dim3(144, 4), 256, 0, stream>>>(fm, ft, Zpart);
    k_g<<<dim3(144, 4), 256, 0, stream>>>(fm, tw, Zpart, Gt);
    k_base<<<dim3(144, 4), 256, 0, stream>>>(ft, tw, tb, out);
    k_main<<<dim3(144, 2, 2), 256, 0, stream>>>(fm, ft, Gt, out);
}

// Round 2
// 745.245 us; speedup vs baseline: 5.5923x; 5.5923x over previous
//
#include <hip/hip_runtime.h>

#define NHW 9216
#define NCH 256
#define SCALE 0.0625f

typedef __attribute__((ext_vector_type(8))) short bfrag;   // 8 bf16 (4 VGPRs)
typedef __attribute__((ext_vector_type(4))) float f32x4;   // MFMA C/D

__device__ __forceinline__ unsigned short f2bf(float x) {  // RNE f32->bf16
    unsigned u = __builtin_bit_cast(unsigned, x);
    u += 0x7FFFu + ((u >> 16) & 1u);
    return (unsigned short)(u >> 16);
}

#define MFMA(a, b, c) __builtin_amdgcn_mfma_f32_16x16x32_bf16((a), (b), (c), 0, 0, 0)

// ---------------------------------------------------------------------------
// Transpose+convert: fm [C][NHW] f32 -> fmT [NHW][C] bf16 (same for ft).
// grid (36, 2 tensors, 2 c-halves), block 256. Reads coalesced; writes are
// per-thread sequential within a row -> L2 merges lines.
// ---------------------------------------------------------------------------
__global__ __launch_bounds__(256) void k_prep(const float* __restrict__ fm,
                                              const float* __restrict__ ft,
                                              unsigned short* __restrict__ fmT,
                                              unsigned short* __restrict__ ftT) {
    const float* src = blockIdx.y ? ft : fm;
    unsigned short* dst = blockIdx.y ? ftT : fmT;
    const int n = blockIdx.x * 256 + threadIdx.x;
    const int c0 = blockIdx.z * 128;
    for (int c = c0; c < c0 + 128; ++c)
        dst[(size_t)n * NCH + c] = f2bf(src[(size_t)c * NHW + n]);
}

__global__ __launch_bounds__(256) void k_prepw(const float* __restrict__ tw,
                                               unsigned short* __restrict__ twb) {
    const int i = blockIdx.x * 256 + threadIdx.x;  // 256*512 elems
    twb[i] = f2bf(tw[i]);
}

// ---------------------------------------------------------------------------
// Z-pass: Zpart[slice][n] = sum over slice's m of exp(SCALE * <fm[:,n],ft[:,m]>)
// grid (72 n-tiles of 128, 4 m-splits of 2304). slice = by*2 + wm (8 slices).
// ---------------------------------------------------------------------------
__global__ __launch_bounds__(256, 2) void k_stats(const unsigned short* __restrict__ fmT,
                                                  const unsigned short* __restrict__ ftT,
                                                  float* __restrict__ Zpart) {
    const int tid = threadIdx.x;
    const int w = tid >> 6, l = tid & 63;
    const int wn = w >> 1, wm = w & 1;
    const int lr = l & 15, lk = l >> 4;
    const int n0 = blockIdx.x * 128;
    const int mbase = blockIdx.y * 2304;
    float zacc[4][4] = {};  // [i][r]

    for (int mt = 0; mt < 18; ++mt) {
        const int m0 = mbase + mt * 128;
        f32x4 acc[4][4] = {};
#pragma unroll
        for (int ks = 0; ks < 8; ++ks) {
            const int k = ks * 32 + lk * 8;
            bfrag a[4], b[4];
#pragma unroll
            for (int i = 0; i < 4; ++i)
                a[i] = *(const bfrag*)(fmT + (size_t)(n0 + wn * 64 + i * 16 + lr) * NCH + k);
#pragma unroll
            for (int j = 0; j < 4; ++j)
                b[j] = *(const bfrag*)(ftT + (size_t)(m0 + wm * 64 + j * 16 + lr) * NCH + k);
#pragma unroll
            for (int i = 0; i < 4; ++i)
#pragma unroll
                for (int j = 0; j < 4; ++j) acc[i][j] = MFMA(a[i], b[j], acc[i][j]);
        }
#pragma unroll
        for (int i = 0; i < 4; ++i)
#pragma unroll
            for (int r = 0; r < 4; ++r) {
                float s = 0.f;
#pragma unroll
                for (int j = 0; j < 4; ++j) s += __expf(acc[i][j][r] * SCALE);
                zacc[i][r] += s;
            }
    }
#pragma unroll
    for (int i = 0; i < 4; ++i)
#pragma unroll
        for (int r = 0; r < 4; ++r) {
            float v = zacc[i][r];
            v += __shfl_xor(v, 1);
            v += __shfl_xor(v, 2);
            v += __shfl_xor(v, 4);
            v += __shfl_xor(v, 8);
            if (lr == 0)
                Zpart[(size_t)(blockIdx.y * 2 + wm) * NHW + n0 + wn * 64 + i * 16 + lk * 4 + r] = v;
        }
}

// ---------------------------------------------------------------------------
// G[o][n] = (W1 @ fm)[o][n] / Z[n], bf16 output. grid (72 n-tiles, 2 o-halves)
// ---------------------------------------------------------------------------
__global__ __launch_bounds__(256) void k_g(const unsigned short* __restrict__ twb,
                                           const unsigned short* __restrict__ fmT,
                                           const float* __restrict__ Zpart,
                                           unsigned short* __restrict__ G) {
    const int tid = threadIdx.x;
    const int w = tid >> 6, l = tid & 63;
    const int wo = w >> 1, wm = w & 1;
    const int lr = l & 15, lk = l >> 4;
    const int n0 = blockIdx.x * 128, o0 = blockIdx.y * 128;
    f32x4 acc[4][4] = {};
#pragma unroll
    for (int ks = 0; ks < 8; ++ks) {
        const int k = ks * 32 + lk * 8;
        bfrag a[4], b[4];
#pragma unroll
        for (int i = 0; i < 4; ++i)
            a[i] = *(const bfrag*)(twb + (size_t)(o0 + wo * 64 + i * 16 + lr) * 512 + k);
#pragma unroll
        for (int j = 0; j < 4; ++j)
            b[j] = *(const bfrag*)(fmT + (size_t)(n0 + wm * 64 + j * 16 + lr) * NCH + k);
#pragma unroll
        for (int i = 0; i < 4; ++i)
#pragma unroll
            for (int j = 0; j < 4; ++j) acc[i][j] = MFMA(a[i], b[j], acc[i][j]);
    }
    float zi[4];
#pragma unroll
    for (int j = 0; j < 4; ++j) {
        const int n = n0 + wm * 64 + j * 16 + lr;
        float z = 0.f;
#pragma unroll
        for (int s = 0; s < 8; ++s) z += Zpart[(size_t)s * NHW + n];
        zi[j] = 1.f / z;
    }
#pragma unroll
    for (int i = 0; i < 4; ++i)
#pragma unroll
        for (int j = 0; j < 4; ++j)
#pragma unroll
            for (int r = 0; r < 4; ++r) {
                const int o = o0 + wo * 64 + i * 16 + lk * 4 + r;
                const int n = n0 + wm * 64 + j * 16 + lr;
                G[(size_t)o * NHW + n] = f2bf(acc[i][j][r] * zi[j]);
            }
}

// ---------------------------------------------------------------------------
// base: out[o][m] = (W2 @ ft)[o][m] + bias[o]. grid (72 m-tiles, 2 o-halves)
// ---------------------------------------------------------------------------
__global__ __launch_bounds__(256) void k_base(const unsigned short* __restrict__ twb,
                                              const unsigned short* __restrict__ ftT,
                                              const float* __restrict__ tb,
                                              float* __restrict__ out) {
    const int tid = threadIdx.x;
    const int w = tid >> 6, l = tid & 63;
    const int wo = w >> 1, wm = w & 1;
    const int lr = l & 15, lk = l >> 4;
    const int m0 = blockIdx.x * 128, o0 = blockIdx.y * 128;
    f32x4 acc[4][4] = {};
#pragma unroll
    for (int ks = 0; ks < 8; ++ks) {
        const int k = ks * 32 + lk * 8;
        bfrag a[4], b[4];
#pragma unroll
        for (int i = 0; i < 4; ++i)
            a[i] = *(const bfrag*)(twb + (size_t)(o0 + wo * 64 + i * 16 + lr) * 512 + 256 + k);
#pragma unroll
        for (int j = 0; j < 4; ++j)
            b[j] = *(const bfrag*)(ftT + (size_t)(m0 + wm * 64 + j * 16 + lr) * NCH + k);
#pragma unroll
        for (int i = 0; i < 4; ++i)
#pragma unroll
            for (int j = 0; j < 4; ++j) acc[i][j] = MFMA(a[i], b[j], acc[i][j]);
    }
#pragma unroll
    for (int i = 0; i < 4; ++i)
#pragma unroll
        for (int j = 0; j < 4; ++j)
#pragma unroll
            for (int r = 0; r < 4; ++r) {
                const int o = o0 + wo * 64 + i * 16 + lk * 4 + r;
                const int m = m0 + wm * 64 + j * 16 + lr;
                out[(size_t)o * NHW + m] = acc[i][j][r] + tb[o];
            }
}

// ---------------------------------------------------------------------------
// main: out[o][m] += sum_n G[o][n] * exp(SCALE * <fm[:,n],ft[:,m]>)
// grid (72 m-tiles, 2 o-halves, 2 n-splits). Per 128-n tile: S-phase (MFMA,
// direct global frags) -> exp -> bf16 E in LDS (B-frag-ready layout) ->
// apply-phase (G frags from global, E frags ds_read_b128).
// ---------------------------------------------------------------------------
__global__ __launch_bounds__(256, 2) void k_main(const unsigned short* __restrict__ fmT,
                                                 const unsigned short* __restrict__ ftT,
                                                 const unsigned short* __restrict__ G,
                                                 float* __restrict__ out) {
    // smE[nc 16][m 128][8] bf16 : element (n,m) at ushort idx (n>>3)*1024 + m*8 + (n&7)
    __shared__ unsigned short smE[16 * 128 * 8];
    const int tid = threadIdx.x;
    const int w = tid >> 6, l = tid & 63;
    const int wn = w >> 1, wm = w & 1;  // S-phase: (n,m); apply: (o,m)
    const int lr = l & 15, lk = l >> 4;
    const int m0 = blockIdx.x * 128;
    const int o0 = blockIdx.y * 128;
    const int ntb = blockIdx.z * 36;
    f32x4 U[4][4] = {};

    for (int nt = ntb; nt < ntb + 36; ++nt) {
        const int n0 = nt * 128;
        // ---- S-phase ----
        f32x4 acc[4][4] = {};
#pragma unroll
        for (int ks = 0; ks < 8; ++ks) {
            const int k = ks * 32 + lk * 8;
            bfrag a[4], b[4];
#pragma unroll
            for (int i = 0; i < 4; ++i)
                a[i] = *(const bfrag*)(fmT + (size_t)(n0 + wn * 64 + i * 16 + lr) * NCH + k);
#pragma unroll
            for (int j = 0; j < 4; ++j)
                b[j] = *(const bfrag*)(ftT + (size_t)(m0 + wm * 64 + j * 16 + lr) * NCH + k);
#pragma unroll
            for (int i = 0; i < 4; ++i)
#pragma unroll
                for (int j = 0; j < 4; ++j) acc[i][j] = MFMA(a[i], b[j], acc[i][j]);
        }
        // ---- E = exp(S*SCALE) -> LDS (bf16, fragment-ready) ----
#pragma unroll
        for (int i = 0; i < 4; ++i)
#pragma unroll
            for (int j = 0; j < 4; ++j) {
                const int nb = wn * 64 + i * 16 + lk * 4;
                const int m = wm * 64 + j * 16 + lr;
                const unsigned lo = (unsigned)f2bf(__expf(acc[i][j][0] * SCALE)) |
                                    ((unsigned)f2bf(__expf(acc[i][j][1] * SCALE)) << 16);
                const unsigned hi = (unsigned)f2bf(__expf(acc[i][j][2] * SCALE)) |
                                    ((unsigned)f2bf(__expf(acc[i][j][3] * SCALE)) << 16);
                uint2 v; v.x = lo; v.y = hi;
                *(uint2*)(&smE[(nb >> 3) * 1024 + m * 8 + (nb & 7)]) = v;
            }
        __syncthreads();
        // ---- apply-phase: U += G(128o x 128n) @ E(128n x 128m) ----
#pragma unroll
        for (int s = 0; s < 4; ++s) {
            bfrag ga[4], eb[4];
#pragma unroll
            for (int i = 0; i < 4; ++i)
                ga[i] = *(const bfrag*)(G + (size_t)(o0 + wn * 64 + i * 16 + lr) * NHW + n0 + s * 32 + lk * 8);
#pragma unroll
            for (int j = 0; j < 4; ++j)
                eb[j] = *(const bfrag*)(&smE[(s * 4 + lk) * 1024 + (wm * 64 + j * 16 + lr) * 8]);
#pragma unroll
            for (int i = 0; i < 4; ++i)
#pragma unroll
                for (int j = 0; j < 4; ++j) U[i][j] = MFMA(ga[i], eb[j], U[i][j]);
        }
        __syncthreads();  // protect smE before next iteration's writes
    }
    // ---- epilogue: accumulate onto base (2 n-split blocks add) ----
#pragma unroll
    for (int i = 0; i < 4; ++i)
#pragma unroll
        for (int j = 0; j < 4; ++j)
#pragma unroll
            for (int r = 0; r < 4; ++r) {
                const int o = o0 + wn * 64 + i * 16 + lk * 4 + r;
                const int m = m0 + wm * 64 + j * 16 + lr;
                atomicAdd(out + (size_t)o * NHW + m, U[i][j][r]);
            }
}

extern "C" void kernel_launch(void* const* d_in, const int* in_sizes, int n_in,
                              void* d_out, int out_size, void* d_ws, size_t ws_size,
                              hipStream_t stream) {
    const float* fm = (const float*)d_in[0];
    const float* ft = (const float*)d_in[1];
    const float* tw = (const float*)d_in[2];
    const float* tb = (const float*)d_in[3];
    float* out = (float*)d_out;

    char* ws = (char*)d_ws;
    float* Zpart = (float*)ws;                                   // 8*9216*4   = 294912
    unsigned short* twb = (unsigned short*)(ws + 294912);        // 256*512*2  = 262144
    unsigned short* fmT = (unsigned short*)(ws + 557056);        // 9216*256*2 = 4718592
    unsigned short* ftT = (unsigned short*)(ws + 5275648);
    unsigned short* G   = (unsigned short*)(ws + 9994240);       // total ~14.7 MB

    k_prep<<<dim3(36, 2, 2), 256, 0, stream>>>(fm, ft, fmT, ftT);
    k_prepw<<<dim3(512), 256, 0, stream>>>(tw, twb);
    k_stats<<<dim3(72, 4), 256, 0, stream>>>(fmT, ftT, Zpart);
    k_g<<<dim3(72, 2), 256, 0, stream>>>(twb, fmT, Zpart, G);
    k_base<<<dim3(72, 2), 256, 0, stream>>>(twb, ftT, tb, out);
    k_main<<<dim3(72, 2, 2), 256, 0, stream>>>(fmT, ftT, G, out);
}

// Round 3
// 418.374 us; speedup vs baseline: 9.9615x; 1.7813x over previous
//
#include <hip/hip_runtime.h>

#define NHW 9216
#define NCH 256
#define SCALE 0.0625f

typedef __attribute__((ext_vector_type(8))) short bfrag;          // 8 bf16
typedef __attribute__((ext_vector_type(4))) float f32x4;          // MFMA C/D
typedef __attribute__((ext_vector_type(8))) unsigned short u16x8;

__device__ __forceinline__ unsigned short f2bf(float x) {  // RNE f32->bf16
    unsigned u = __builtin_bit_cast(unsigned, x);
    u += 0x7FFFu + ((u >> 16) & 1u);
    return (unsigned short)(u >> 16);
}

#define MFMA(a, b, c) __builtin_amdgcn_mfma_f32_16x16x32_bf16((a), (b), (c), 0, 0, 0)

// ---------------------------------------------------------------------------
// LDS-tiled transpose+convert: src [256 c][9216 n] f32 -> dst [9216 n][256 c] bf16
// grid (144 n-tiles of 64, 2 tensors), block 256.
// ---------------------------------------------------------------------------
__global__ __launch_bounds__(256) void k_prep(const float* __restrict__ fm,
                                              const float* __restrict__ ft,
                                              unsigned short* __restrict__ fmT,
                                              unsigned short* __restrict__ ftT) {
    __shared__ float smT[64][257];
    const float* src = blockIdx.y ? ft : fm;
    unsigned short* dst = blockIdx.y ? ftT : fmT;
    const int t = threadIdx.x;
    const int n0 = blockIdx.x * 64;
    {   // stage 1: coalesced reads (lane = n), LDS write conflict-free (pad 257)
        const int n = t & 63;
        const int cb = t >> 6;
        for (int p = 0; p < 64; ++p) {
            const int c = p * 4 + cb;
            smT[n][c] = src[(size_t)c * NHW + n0 + n];
        }
    }
    __syncthreads();
    {   // stage 2: each thread emits 16B bf16 chunks of one n-row
        const int n = t >> 2;
        const int c0 = (t & 3) * 64;
#pragma unroll
        for (int cc = 0; cc < 64; cc += 8) {
            const float4 v0 = *(const float4*)(&smT[n][c0 + cc]);
            const float4 v1 = *(const float4*)(&smT[n][c0 + cc + 4]);
            u16x8 o;
            o[0] = f2bf(v0.x); o[1] = f2bf(v0.y); o[2] = f2bf(v0.z); o[3] = f2bf(v0.w);
            o[4] = f2bf(v1.x); o[5] = f2bf(v1.y); o[6] = f2bf(v1.z); o[7] = f2bf(v1.w);
            *(u16x8*)(dst + (size_t)(n0 + n) * NCH + c0 + cc) = o;
        }
    }
}

__global__ __launch_bounds__(256) void k_prepw(const float* __restrict__ tw,
                                               unsigned short* __restrict__ twb) {
    const int i = blockIdx.x * 256 + threadIdx.x;
    twb[i] = f2bf(tw[i]);
}

// ---------------------------------------------------------------------------
// Z-pass: Zpart[slice][n] = partial sum_m exp(SCALE*<fm[:,n],ft[:,m]>)
// grid (72 n-tiles of 128, 8 m-splits of 1152). 4 waves, each 64n x 64m.
// slice = by*2 + wm (16 slices).
// ---------------------------------------------------------------------------
__global__ __launch_bounds__(256, 3) void k_stats(const unsigned short* __restrict__ fmT,
                                                  const unsigned short* __restrict__ ftT,
                                                  float* __restrict__ Zpart) {
    const int t = threadIdx.x;
    const int w = t >> 6, l = t & 63;
    const int wn = w >> 1, wm = w & 1;
    const int lr = l & 15, lk = l >> 4;
    const int n0 = blockIdx.x * 128 + wn * 64;
    const int mb = blockIdx.y * 1152 + wm * 64;
    float zacc[4][4] = {};

    for (int mt = 0; mt < 9; ++mt) {
        const int m0 = mb + mt * 128;
        f32x4 acc[4][4] = {};
#pragma unroll
        for (int ks = 0; ks < 8; ++ks) {
            const int k = ks * 32 + lk * 8;
            bfrag a[4], b[4];
#pragma unroll
            for (int i = 0; i < 4; ++i)
                a[i] = *(const bfrag*)(fmT + (size_t)(n0 + i * 16 + lr) * NCH + k);
#pragma unroll
            for (int j = 0; j < 4; ++j)
                b[j] = *(const bfrag*)(ftT + (size_t)(m0 + j * 16 + lr) * NCH + k);
#pragma unroll
            for (int i = 0; i < 4; ++i)
#pragma unroll
                for (int j = 0; j < 4; ++j) acc[i][j] = MFMA(a[i], b[j], acc[i][j]);
        }
#pragma unroll
        for (int i = 0; i < 4; ++i)
#pragma unroll
            for (int r = 0; r < 4; ++r) {
                float s = 0.f;
#pragma unroll
                for (int j = 0; j < 4; ++j) s += __expf(acc[i][j][r] * SCALE);
                zacc[i][r] += s;
            }
    }
#pragma unroll
    for (int i = 0; i < 4; ++i)
#pragma unroll
        for (int r = 0; r < 4; ++r) {
            float v = zacc[i][r];
            v += __shfl_xor(v, 1);
            v += __shfl_xor(v, 2);
            v += __shfl_xor(v, 4);
            v += __shfl_xor(v, 8);
            if (lr == 0)
                Zpart[(size_t)(blockIdx.y * 2 + wm) * NHW + n0 + i * 16 + lk * 4 + r] = v;
        }
}

// ---------------------------------------------------------------------------
// G[o][n] = (W1 @ fm)[o][n] / Z[n], bf16. grid (72 n-tiles, 2 o-halves).
// ---------------------------------------------------------------------------
__global__ __launch_bounds__(256) void k_g(const unsigned short* __restrict__ twb,
                                           const unsigned short* __restrict__ fmT,
                                           const float* __restrict__ Zpart,
                                           unsigned short* __restrict__ G) {
    const int tid = threadIdx.x;
    const int w = tid >> 6, l = tid & 63;
    const int wo = w >> 1, wm = w & 1;
    const int lr = l & 15, lk = l >> 4;
    const int n0 = blockIdx.x * 128, o0 = blockIdx.y * 128;
    f32x4 acc[4][4] = {};
#pragma unroll
    for (int ks = 0; ks < 8; ++ks) {
        const int k = ks * 32 + lk * 8;
        bfrag a[4], b[4];
#pragma unroll
        for (int i = 0; i < 4; ++i)
            a[i] = *(const bfrag*)(twb + (size_t)(o0 + wo * 64 + i * 16 + lr) * 512 + k);
#pragma unroll
        for (int j = 0; j < 4; ++j)
            b[j] = *(const bfrag*)(fmT + (size_t)(n0 + wm * 64 + j * 16 + lr) * NCH + k);
#pragma unroll
        for (int i = 0; i < 4; ++i)
#pragma unroll
            for (int j = 0; j < 4; ++j) acc[i][j] = MFMA(a[i], b[j], acc[i][j]);
    }
    float zi[4];
#pragma unroll
    for (int j = 0; j < 4; ++j) {
        const int n = n0 + wm * 64 + j * 16 + lr;
        float z = 0.f;
#pragma unroll
        for (int s = 0; s < 16; ++s) z += Zpart[(size_t)s * NHW + n];
        zi[j] = 1.f / z;
    }
#pragma unroll
    for (int i = 0; i < 4; ++i)
#pragma unroll
        for (int j = 0; j < 4; ++j)
#pragma unroll
            for (int r = 0; r < 4; ++r) {
                const int o = o0 + wo * 64 + i * 16 + lk * 4 + r;
                const int n = n0 + wm * 64 + j * 16 + lr;
                G[(size_t)o * NHW + n] = f2bf(acc[i][j][r] * zi[j]);
            }
}

// ---------------------------------------------------------------------------
// base: out[o][m] = (W2 @ ft)[o][m] + bias[o]. grid (72 m-tiles, 2 o-halves).
// ---------------------------------------------------------------------------
__global__ __launch_bounds__(256) void k_base(const unsigned short* __restrict__ twb,
                                              const unsigned short* __restrict__ ftT,
                                              const float* __restrict__ tb,
                                              float* __restrict__ out) {
    const int tid = threadIdx.x;
    const int w = tid >> 6, l = tid & 63;
    const int wo = w >> 1, wm = w & 1;
    const int lr = l & 15, lk = l >> 4;
    const int m0 = blockIdx.x * 128, o0 = blockIdx.y * 128;
    f32x4 acc[4][4] = {};
#pragma unroll
    for (int ks = 0; ks < 8; ++ks) {
        const int k = ks * 32 + lk * 8;
        bfrag a[4], b[4];
#pragma unroll
        for (int i = 0; i < 4; ++i)
            a[i] = *(const bfrag*)(twb + (size_t)(o0 + wo * 64 + i * 16 + lr) * 512 + 256 + k);
#pragma unroll
        for (int j = 0; j < 4; ++j)
            b[j] = *(const bfrag*)(ftT + (size_t)(m0 + wm * 64 + j * 16 + lr) * NCH + k);
#pragma unroll
        for (int i = 0; i < 4; ++i)
#pragma unroll
            for (int j = 0; j < 4; ++j) acc[i][j] = MFMA(a[i], b[j], acc[i][j]);
    }
#pragma unroll
    for (int i = 0; i < 4; ++i)
#pragma unroll
        for (int j = 0; j < 4; ++j)
#pragma unroll
            for (int r = 0; r < 4; ++r) {
                const int o = o0 + wo * 64 + i * 16 + lk * 4 + r;
                const int m = m0 + wm * 64 + j * 16 + lr;
                out[(size_t)o * NHW + m] = acc[i][j][r] + tb[o];
            }
}

// ---------------------------------------------------------------------------
// main: out[o][m] += sum_n G[o][n] * exp(SCALE*<fm[:,n],ft[:,m]>)
// grid (144 m-tiles of 64, 8 n-splits of 9 n-tiles). Block = 4 waves, o-FULL:
// S-phase: wave w computes S[32n x 64m]; apply: wave w owns o in [w*64,w*64+64).
// ftT m-tile staged once in LDS; E tile bf16 in LDS (frag-ready layout).
// ---------------------------------------------------------------------------
__global__ __launch_bounds__(256, 3) void k_main(const unsigned short* __restrict__ fmT,
                                                 const unsigned short* __restrict__ ftT,
                                                 const unsigned short* __restrict__ G,
                                                 float* __restrict__ out) {
    __shared__ unsigned short smB[32 * 64 * 8];  // ftT tile [kc 32][m 64][8]  (32 KB)
    __shared__ unsigned short smE[16 * 64 * 8];  // E tile  [nc 16][m 64][8]  (16 KB)
    const int t = threadIdx.x;
    const int w = t >> 6, l = t & 63;
    const int lr = l & 15, lk = l >> 4;
    const int m0 = blockIdx.x * 64;
    const int ntb = blockIdx.y * 9;

    {   // stage ftT[m0..m0+64][0..256] -> smB
        const int m = t >> 2;
        const int kc0 = t & 3;
#pragma unroll
        for (int p = 0; p < 8; ++p) {
            const int kc = p * 4 + kc0;
            const bfrag v = *(const bfrag*)(ftT + (size_t)(m0 + m) * NCH + kc * 8);
            *(bfrag*)(&smB[(kc * 64 + m) * 8]) = v;
        }
    }
    __syncthreads();

    f32x4 U[4][4] = {};
    for (int nt = ntb; nt < ntb + 9; ++nt) {
        const int n0 = nt * 128;
        // ---- S-phase: S[w*32..+32, 0..64] ----
        f32x4 acc[2][4] = {};
#pragma unroll
        for (int ks = 0; ks < 8; ++ks) {
            const int k = ks * 32 + lk * 8;
            bfrag a[2], b[4];
#pragma unroll
            for (int i = 0; i < 2; ++i)
                a[i] = *(const bfrag*)(fmT + (size_t)(n0 + w * 32 + i * 16 + lr) * NCH + k);
#pragma unroll
            for (int j = 0; j < 4; ++j)
                b[j] = *(const bfrag*)(&smB[((ks * 4 + lk) * 64 + j * 16 + lr) * 8]);
#pragma unroll
            for (int i = 0; i < 2; ++i)
#pragma unroll
                for (int j = 0; j < 4; ++j) acc[i][j] = MFMA(a[i], b[j], acc[i][j]);
        }
        // ---- E = exp(S*SCALE) -> smE (frag-ready) ----
#pragma unroll
        for (int i = 0; i < 2; ++i)
#pragma unroll
            for (int j = 0; j < 4; ++j) {
                const int nb = w * 32 + i * 16 + lk * 4;
                const int m = j * 16 + lr;
                const unsigned lo = (unsigned)f2bf(__expf(acc[i][j][0] * SCALE)) |
                                    ((unsigned)f2bf(__expf(acc[i][j][1] * SCALE)) << 16);
                const unsigned hi = (unsigned)f2bf(__expf(acc[i][j][2] * SCALE)) |
                                    ((unsigned)f2bf(__expf(acc[i][j][3] * SCALE)) << 16);
                uint2 v; v.x = lo; v.y = hi;
                *(uint2*)(&smE[((nb >> 3) * 64 + m) * 8 + (nb & 7)]) = v;
            }
        __syncthreads();
        // ---- apply: U[w*64..+64, m0..+64] += G @ E ----
#pragma unroll
        for (int s = 0; s < 4; ++s) {
            bfrag ga[4], eb[4];
#pragma unroll
            for (int i = 0; i < 4; ++i)
                ga[i] = *(const bfrag*)(G + (size_t)(w * 64 + i * 16 + lr) * NHW + n0 + s * 32 + lk * 8);
#pragma unroll
            for (int j = 0; j < 4; ++j)
                eb[j] = *(const bfrag*)(&smE[((s * 4 + lk) * 64 + j * 16 + lr) * 8]);
#pragma unroll
            for (int i = 0; i < 4; ++i)
#pragma unroll
                for (int j = 0; j < 4; ++j) U[i][j] = MFMA(ga[i], eb[j], U[i][j]);
        }
        __syncthreads();  // protect smE before next iteration's writes
    }
    // ---- epilogue: atomic accumulate onto base ----
#pragma unroll
    for (int i = 0; i < 4; ++i)
#pragma unroll
        for (int j = 0; j < 4; ++j)
#pragma unroll
            for (int r = 0; r < 4; ++r) {
                const int o = w * 64 + i * 16 + lk * 4 + r;
                const int m = m0 + j * 16 + lr;
                atomicAdd(out + (size_t)o * NHW + m, U[i][j][r]);
            }
}

extern "C" void kernel_launch(void* const* d_in, const int* in_sizes, int n_in,
                              void* d_out, int out_size, void* d_ws, size_t ws_size,
                              hipStream_t stream) {
    const float* fm = (const float*)d_in[0];
    const float* ft = (const float*)d_in[1];
    const float* tw = (const float*)d_in[2];
    const float* tb = (const float*)d_in[3];
    float* out = (float*)d_out;

    char* ws = (char*)d_ws;
    float* Zpart = (float*)ws;                                 // 16*9216*4  = 589824
    unsigned short* twb = (unsigned short*)(ws + 589824);      // 256*512*2  = 262144
    unsigned short* fmT = (unsigned short*)(ws + 851968);      // 9216*256*2 = 4718592
    unsigned short* ftT = (unsigned short*)(ws + 5570560);
    unsigned short* G   = (unsigned short*)(ws + 10289152);    // total ~15.0 MB

    k_prep<<<dim3(144, 2), 256, 0, stream>>>(fm, ft, fmT, ftT);
    k_prepw<<<dim3(512), 256, 0, stream>>>(tw, twb);
    k_stats<<<dim3(72, 8), 256, 0, stream>>>(fmT, ftT, Zpart);
    k_g<<<dim3(72, 2), 256, 0, stream>>>(twb, fmT, Zpart, G);
    k_base<<<dim3(72, 2), 256, 0, stream>>>(twb, ftT, tb, out);
    k_main<<<dim3(144, 8), 256, 0, stream>>>(fmT, ftT, G, out);
}